// Round 13
// baseline (241.671 us; speedup 1.0000x reference)
//
#include <hip/hip_runtime.h>

using bf16_t = __bf16;
typedef __bf16 bf16x4 __attribute__((ext_vector_type(4)));
typedef __bf16 bf16x8 __attribute__((ext_vector_type(8)));
typedef float floatx4 __attribute__((ext_vector_type(4)));

#define MFMA_BF16(a, b, c) __builtin_amdgcn_mfma_f32_16x16x32_bf16((a), (b), (c), 0, 0, 0)

__device__ __forceinline__ void async_ld16(bf16_t* lds_dst, const bf16_t* g_src) {
    __builtin_amdgcn_global_load_lds(
        (const __attribute__((address_space(1))) void*)g_src,
        (__attribute__((address_space(3))) void*)lds_dst, 16, 0, 0);
}

// ---------------------------------------------------------------------------
// Fused fp32->bf16 casts (x, Wqkv, Wproj) + lam, one launch.
// Blocks 0..1023: x; 1024..4095: Wqkv; 4096..5119: Wproj; 5120: lam.
// ---------------------------------------------------------------------------
__global__ __launch_bounds__(256) void cast_all(const float* __restrict__ x,
                                                const float* __restrict__ Wqkv,
                                                const float* __restrict__ Wproj,
                                                const float* __restrict__ lq1,
                                                const float* __restrict__ lq2,
                                                const float* __restrict__ lk1,
                                                const float* __restrict__ lk2,
                                                bf16_t* __restrict__ xb,
                                                bf16_t* __restrict__ Wqkvb,
                                                bf16_t* __restrict__ Wprojb,
                                                float* __restrict__ lamp) {
    const int b = blockIdx.x;
    if (b == 5120) {
        int l = threadIdx.x;
        if (l < 64) {
            float p1 = lq1[l] * lk1[l];
            float p2 = lq2[l] * lk2[l];
            #pragma unroll
            for (int d = 1; d < 64; d <<= 1) {
                p1 += __shfl_xor(p1, d);
                p2 += __shfl_xor(p2, d);
            }
            if (l == 0) *lamp = expf(p1) - expf(p2) + 0.2f;
        }
        return;
    }
    const float* src;
    bf16_t* dst;
    size_t i;
    if (b < 1024)      { src = x;     dst = xb;     i = (size_t)b * 256 + threadIdx.x; }
    else if (b < 4096) { src = Wqkv;  dst = Wqkvb;  i = (size_t)(b - 1024) * 256 + threadIdx.x; }
    else               { src = Wproj; dst = Wprojb; i = (size_t)(b - 4096) * 256 + threadIdx.x; }
    const floatx4 a = *(const floatx4*)(src + i * 8);
    const floatx4 c = *(const floatx4*)(src + i * 8 + 4);
    bf16x8 r;
    r[0] = (bf16_t)a[0]; r[1] = (bf16_t)a[1]; r[2] = (bf16_t)a[2]; r[3] = (bf16_t)a[3];
    r[4] = (bf16_t)c[0]; r[5] = (bf16_t)c[1]; r[6] = (bf16_t)c[2]; r[7] = (bf16_t)c[3];
    *(bf16x8*)(dst + i * 8) = r;
}

// ---------------------------------------------------------------------------
// QKV GEMM with FUSED ROTARY, v16 = 8 waves + BK=64 + dbuf.
// R7's BK=64 failure was fragment-VGPR blowup at 4 waves (192 regs); at
// 8 waves (2Mx4N, per-wave 64x32 out) state is a[4][2]+b[2][2]+acc[4][2]
// = 80 VGPRs, and the K-loop drops 32->16 iters -> HALF the barrier/drain
// sync points (the 2-phase critical path, proven -8us on proj in R8).
// LDS 64 KB -> 2 blocks/CU -> 16 waves/CU.
// Column remap (R12-proven): block bx covers head hh=bx&15 of pair
// p=bx>>4 (0=Q,1=K,2=V), staged B row (col c'=jt*16+rr) = p*2048 +
// (jt&1)*1024 + hh*64 + (jt>>1)*16 + rr. At 8 waves: jt = wc*2+j ->
// inst=j, e=wc*16+m16; rotation thread-local on f32 acc, 16 sincos/thread.
// ---------------------------------------------------------------------------
__global__ __launch_bounds__(512, 4) void gemm_qkv_rot(const bf16_t* __restrict__ A,
                                                       const bf16_t* __restrict__ B,
                                                       bf16_t* __restrict__ Qb,
                                                       bf16_t* __restrict__ Kb,
                                                       bf16_t* __restrict__ Vt) {
    constexpr int K = 1024, BM = 128, BK = 64;
    __shared__ __align__(16) bf16_t As[2][BM * BK];   // 32 KB
    __shared__ __align__(16) bf16_t Bs[2][BM * BK];   // 32 KB
    const int t = threadIdx.x;
    const int lane = t & 63, wave = t >> 6;           // 0..7
    const int q4 = lane >> 4, m16 = lane & 15;
    const int mblk = blockIdx.y * BM;
    const int p = blockIdx.x >> 4, hh = blockIdx.x & 15;
    const int pbase = p * 2048 + hh * 64;
    const int wr = wave >> 2, wc = wave & 3;          // 2 x 4 wave grid

    auto stage = [&](int buf, int k0) {
        #pragma unroll
        for (int rr = 0; rr < 2; ++rr) {
            int f = rr * 512 + t;        // row = f>>3, 16B chunk = f&7
            async_ld16(&As[buf][f * 8], &A[(size_t)(mblk + (f >> 3)) * K + k0 + (f & 7) * 8]);
        }
        #pragma unroll
        for (int rr = 0; rr < 2; ++rr) {
            int f = rr * 512 + t;
            int rp = f >> 3, jt = rp >> 4;
            int Brow = pbase + (jt & 1) * 1024 + ((jt >> 1) * 16) + (rp & 15);
            async_ld16(&Bs[buf][f * 8], &B[(size_t)Brow * K + k0 + (f & 7) * 8]);
        }
    };

    floatx4 acc[4][2] = {};
    stage(0, 0);

    for (int it = 0; it < 16; ++it) {
        const int cur = it & 1;
        __syncthreads();   // buf[cur] staged & visible; prev reads done
        if (it + 1 < 16) stage(cur ^ 1, (it + 1) * BK);

        bf16x8 a[4][2], b[2][2];
        #pragma unroll
        for (int i = 0; i < 4; ++i)
            #pragma unroll
            for (int kk = 0; kk < 2; ++kk)
                a[i][kk] = *(const bf16x8*)&As[cur][(wr * 64 + i * 16 + m16) * BK + kk * 32 + q4 * 8];
        #pragma unroll
        for (int j = 0; j < 2; ++j)
            #pragma unroll
            for (int kk = 0; kk < 2; ++kk)
                b[j][kk] = *(const bf16x8*)&Bs[cur][(wc * 32 + j * 16 + m16) * BK + kk * 32 + q4 * 8];
        __builtin_amdgcn_s_setprio(1);
        #pragma unroll
        for (int i = 0; i < 4; ++i)
            #pragma unroll
            for (int j = 0; j < 2; ++j)
                #pragma unroll
                for (int kk = 0; kk < 2; ++kk)
                    acc[i][j] = MFMA_BF16(a[i][kk], b[j][kk], acc[i][j]);
        __builtin_amdgcn_s_setprio(0);
    }

    if (p < 2) {
        bf16_t* dst = (p == 0) ? Qb : Kb;
        const int e = wc * 16 + m16;
        const float invf = exp2f(-(float)e * (13.287712379549449f / 64.0f));
        #pragma unroll
        for (int i = 0; i < 4; ++i) {
            int mbase = mblk + wr * 64 + i * 16 + q4 * 4;
            #pragma unroll
            for (int r = 0; r < 4; ++r) {
                int m = mbase + r;
                float sn, cs;
                sincosf((float)m * invf, &sn, &cs);
                float v1 = acc[i][0][r], v2 = acc[i][1][r];
                dst[(size_t)(hh * 2048 + m) * 64 + e]        = (bf16_t)(v1 * cs - v2 * sn);
                dst[(size_t)((16 + hh) * 2048 + m) * 64 + e] = (bf16_t)(v2 * cs + v1 * sn);
            }
        }
    } else {
        const int e = wc * 16 + m16;
        #pragma unroll
        for (int i = 0; i < 4; ++i) {
            int mbase = mblk + wr * 64 + i * 16 + q4 * 4;
            #pragma unroll
            for (int j = 0; j < 2; ++j) {   // j == inst
                bf16x4 pv;
                #pragma unroll
                for (int r = 0; r < 4; ++r) pv[r] = (bf16_t)acc[i][j][r];
                *(bf16x4*)&Vt[(size_t)(hh * 128 + j * 64 + e) * 2048 + mbase] = pv;
            }
        }
    }
}

// ---------------------------------------------------------------------------
// GEMM (bf16), dbuf 2-phase (R10-proven) — proj only.
// ---------------------------------------------------------------------------
template <int BM, int BN, int BK>
__global__ __launch_bounds__(256) void gemm_bt(const bf16_t* __restrict__ A,
                                               const bf16_t* __restrict__ B,
                                               float* __restrict__ C,
                                               int M, int N, int K) {
    constexpr int KC = BK / 32;
    constexpr int CH = BK / 8;
    constexpr int AR = BM * BK / 2048;
    constexpr int BR = BN * BK / 2048;
    __shared__ __align__(16) bf16_t As[2][BM * BK];
    __shared__ __align__(16) bf16_t Bs[2][BN * BK];
    const int t = threadIdx.x;
    const int lane = t & 63, wave = t >> 6;
    const int q4 = lane >> 4, m16 = lane & 15;
    const int mblk = blockIdx.y * BM, nblk = blockIdx.x * BN;
    const int wr = wave >> 1, wc = wave & 1;
    constexpr int WM = BM / 2, WN = BN / 2;
    constexpr int NI = WM / 16, NJ = WN / 16;

    auto stage = [&](int buf, int k0) {
        #pragma unroll
        for (int rr = 0; rr < AR; ++rr) {
            int f = rr * 256 + t;
            async_ld16(&As[buf][f * 8], &A[(size_t)(mblk + f / CH) * K + k0 + (f % CH) * 8]);
        }
        #pragma unroll
        for (int rr = 0; rr < BR; ++rr) {
            int f = rr * 256 + t;
            async_ld16(&Bs[buf][f * 8], &B[(size_t)(nblk + f / CH) * K + k0 + (f % CH) * 8]);
        }
    };

    floatx4 acc[NI][NJ] = {};
    stage(0, 0);  // prologue

    const int NTK = K / BK;
    for (int it = 0; it < NTK; ++it) {
        const int cur = it & 1;
        __syncthreads();
        if (it + 1 < NTK) stage(cur ^ 1, (it + 1) * BK);

        bf16x8 a[NI][KC], b[NJ][KC];
        #pragma unroll
        for (int i = 0; i < NI; ++i)
            #pragma unroll
            for (int kk = 0; kk < KC; ++kk)
                a[i][kk] = *(const bf16x8*)&As[cur][(wr * WM + i * 16 + m16) * BK + kk * 32 + q4 * 8];
        #pragma unroll
        for (int j = 0; j < NJ; ++j)
            #pragma unroll
            for (int kk = 0; kk < KC; ++kk)
                b[j][kk] = *(const bf16x8*)&Bs[cur][(wc * WN + j * 16 + m16) * BK + kk * 32 + q4 * 8];
        __builtin_amdgcn_s_setprio(1);
        #pragma unroll
        for (int i = 0; i < NI; ++i)
            #pragma unroll
            for (int j = 0; j < NJ; ++j)
                #pragma unroll
                for (int kk = 0; kk < KC; ++kk)
                    acc[i][j] = MFMA_BF16(a[i][kk], b[j][kk], acc[i][j]);
        __builtin_amdgcn_s_setprio(0);
    }

    #pragma unroll
    for (int i = 0; i < NI; ++i)
        #pragma unroll
        for (int j = 0; j < NJ; ++j) {
            int n = nblk + wc * WN + j * 16 + m16;
            int mbase = mblk + wr * WM + i * 16 + q4 * 4;
            #pragma unroll
            for (int r = 0; r < 4; ++r)
                C[(size_t)(mbase + r) * N + n] = acc[i][j][r];
        }
}

// ---------------------------------------------------------------------------
// Differential flash attention, v8 — FROZEN (proven 90.4-94us).
// Restructure history: v9 (cross-wave P + swapped QK) -> register blowup;
// v10 (K reg-prefetch) -> allocator sank loads across barrier; v12
// (cross-wave P + mid-iter barrier) -> lockstep killed wave-drift overlap.
// The wave-private P + single-barrier structure is load-bearing.
// ---------------------------------------------------------------------------
__global__ __launch_bounds__(512, 4) void flash_diff(const bf16_t* __restrict__ Qb,
                                                     const bf16_t* __restrict__ Kb,
                                                     const bf16_t* __restrict__ Vt,
                                                     const float* __restrict__ lamp,
                                                     bf16_t* __restrict__ Ao) {
    constexpr int N = 2048, BN = 64, NT = N / BN;  // 32 chunks
    __shared__ __align__(16) bf16_t smem[40960];   // 80 KB
    // buf b: Kf = smem + b*16384 (16 spans x 512), Vf = Kf + 8192
    bf16_t* Pf = smem + 32768;                     // [8 waves][2 half][512] 16 KB
    const int t = threadIdx.x, lane = t & 63, w = t >> 6;   // w in 0..7
    const int comp = w >> 2, w4 = w & 3;
    const int q4 = lane >> 4, m16 = lane & 15;
    const int Lb = blockIdx.x;
    const int virt = (Lb & 7) * 64 + (Lb >> 3);
    const int h = virt >> 5, qt = virt & 31;
    const float lam = *lamp;
    const float cexp = 0.125f * 1.4426950408889634f;  // scale * log2(e)

    // Q fragments for this wave's component (A-operand: m=m16 -> qrow)
    bf16x8 qf[2];
    const int qrow = qt * 64 + w4 * 16 + m16;
    #pragma unroll
    for (int kc = 0; kc < 2; ++kc)
        qf[kc] = *(const bf16x8*)&Qb[(size_t)((comp * 16 + h) * 2048 + qrow) * 64 + kc * 32 + q4 * 8];

    bf16x8 ones;
    #pragma unroll
    for (int j = 0; j < 8; ++j) ones[j] = (bf16_t)1.0f;

    floatx4 O[8] = {};
    floatx4 sm = {};

    auto stage = [&](bf16_t* Kd, bf16_t* Vd, int k0) {
        #pragma unroll
        for (int rr = 0; rr < 4; ++rr) {
            int idx = w * 4 + rr;
            if (idx < 16) {
                int i = idx >> 3, s = (idx >> 1) & 3, half = idx & 1;
                async_ld16(&Kd[idx * 512],
                           &Kb[(size_t)((i * 16 + h) * 2048 + k0 + 16 * s + m16) * 64 + half * 32 + q4 * 8]);
            } else {
                int v = idx - 16, tt = v >> 1, half = v & 1;
                async_ld16(&Vd[v * 512],
                           &Vt[(size_t)(h * 128 + tt * 16 + m16) * 2048 + k0 + half * 32 + q4 * 8]);
            }
        }
    };

    stage(smem, smem + 8192, 0);  // prologue: chunk 0 -> buf 0

    for (int it = 0; it < NT; ++it) {
        const int cur = it & 1;
        bf16_t* Kf = smem + cur * 16384;
        bf16_t* Vf = Kf + 8192;
        __syncthreads();
        if (it + 1 < NT) {
            bf16_t* Kn = smem + (cur ^ 1) * 16384;
            stage(Kn, Kn + 8192, (it + 1) * BN);
        }

        // ---- S = Q K^T (one component), p = exp2(S*cexp), swizzled P-store ----
        bf16_t* pw = &Pf[w * 1024];
        __builtin_amdgcn_s_setprio(1);
        #pragma unroll
        for (int s = 0; s < 4; ++s) {
            floatx4 sacc = {};
            const bf16x8 kf0 = *(const bf16x8*)&Kf[((comp * 4 + s) * 2 + 0) * 512 + lane * 8];
            const bf16x8 kf1 = *(const bf16x8*)&Kf[((comp * 4 + s) * 2 + 1) * 512 + lane * 8];
            sacc = MFMA_BF16(qf[0], kf0, sacc);  // D[qrow][key]
            sacc = MFMA_BF16(qf[1], kf1, sacc);
            __builtin_amdgcn_s_setprio(0);
            const int half = s >> 1, quad = (2 * s + (m16 >> 3)) & 3, jj = m16 & 7;
            #pragma unroll
            for (int r = 0; r < 4; ++r) {
                int u = quad * 16 + q4 * 4 + r;
                pw[half * 512 + (u ^ quad) * 8 + jj] = (bf16_t)exp2f(sacc[r] * cexp);
            }
            __builtin_amdgcn_s_setprio(1);
        }
        __builtin_amdgcn_s_setprio(0);
        // Pf region is wave-private: store->read ordered by intra-wave lgkmcnt.

        // ---- P reads (swizzled contiguous b128), row sums, PV ----
        bf16x8 pf[2];
        const int ur = lane ^ q4;  // (q4*16+m16) ^ (u>>4)
        pf[0] = *(const bf16x8*)&pw[0 * 512 + ur * 8];
        pf[1] = *(const bf16x8*)&pw[1 * 512 + ur * 8];
        sm = MFMA_BF16(pf[0], ones, sm);
        sm = MFMA_BF16(pf[1], ones, sm);
        __builtin_amdgcn_s_setprio(1);
        #pragma unroll
        for (int tt = 0; tt < 8; ++tt) {
            const bf16x8 vf0 = *(const bf16x8*)&Vf[(tt * 2 + 0) * 512 + lane * 8];
            const bf16x8 vf1 = *(const bf16x8*)&Vf[(tt * 2 + 1) * 512 + lane * 8];
            O[tt] = MFMA_BF16(pf[0], vf0, O[tt]);
            O[tt] = MFMA_BF16(pf[1], vf1, O[tt]);
        }
        __builtin_amdgcn_s_setprio(0);
    }

    // ---- epilogue: Ao[n][h*128+vc] = O0/l0 - lam*O1/l1 ----
    float inv[4];
    #pragma unroll
    for (int r = 0; r < 4; ++r) inv[r] = 1.0f / sm[r];

    float* Ff = (float*)smem;  // reuse buf0: [w4][col 128][row 16] f32 = 32 KB
    __syncthreads();           // all LDS traffic of last chunk done
    if (comp == 1) {
        #pragma unroll
        for (int tt = 0; tt < 8; ++tt) {
            floatx4 val;
            #pragma unroll
            for (int r = 0; r < 4; ++r) val[r] = lam * O[tt][r] * inv[r];
            *(floatx4*)&Ff[((w4 * 128 + tt * 16 + m16) << 4) + q4 * 4] = val;
        }
    }
    __syncthreads();
    if (comp == 0) {
        const int orow = qt * 64 + w4 * 16 + q4 * 4;
        #pragma unroll
        for (int tt = 0; tt < 8; ++tt) {
            const floatx4 v1 = *(const floatx4*)&Ff[((w4 * 128 + tt * 16 + m16) << 4) + q4 * 4];
            #pragma unroll
            for (int r = 0; r < 4; ++r) {
                float val = O[tt][r] * inv[r] - v1[r];
                Ao[(size_t)(orow + r) * 2048 + h * 128 + tt * 16 + m16] = (bf16_t)val;
            }
        }
    }
}

// ---------------------------------------------------------------------------
extern "C" void kernel_launch(void* const* d_in, const int* in_sizes, int n_in,
                              void* d_out, int out_size, void* d_ws, size_t ws_size,
                              hipStream_t stream) {
    const float* x     = (const float*)d_in[0];
    const float* Wqkv  = (const float*)d_in[1];
    const float* Wproj = (const float*)d_in[2];
    const float* lq1   = (const float*)d_in[3];
    const float* lq2   = (const float*)d_in[4];
    const float* lk1   = (const float*)d_in[5];
    const float* lk2   = (const float*)d_in[6];
    float* out = (float*)d_out;

    char* ws = (char*)d_ws;
    bf16_t* xb     = (bf16_t*)(ws);               //  4,194,304 B
    bf16_t* Ao     = (bf16_t*)(ws);               //  aliases xb/Wqkvb (dead post-QKV)
    bf16_t* Wqkvb  = (bf16_t*)(ws + 4194304);     // 12,582,912 B
    bf16_t* Wprojb = (bf16_t*)(ws + 16777216);    //  4,194,304 B
    bf16_t* Qb     = (bf16_t*)(ws + 20971520);    //  8,388,608 B
    bf16_t* Kb     = (bf16_t*)(ws + 29360128);    //  8,388,608 B
    bf16_t* Vt     = (bf16_t*)(ws + 37748736);    //  8,388,608 B
    float*  lamp   = (float*)(ws + 46137344);     //  4 B (total ~46.1 MB)

    // 4 launches: fused casts+lam, QKV GEMM w/ fused rotary (8w BK64),
    // flash (v8 frozen), proj (BK=64, dbuf).
    cast_all<<<5121, 256, 0, stream>>>(x, Wqkv, Wproj, lq1, lq2, lk1, lk2,
                                       xb, Wqkvb, Wprojb, lamp);
    gemm_qkv_rot<<<dim3(48, 16), 512, 0, stream>>>(xb, Wqkvb, Qb, Kb, Vt);
    flash_diff<<<512, 512, 0, stream>>>(Qb, Kb, Vt, lamp, Ao);
    gemm_bt<64, 64, 64><<<dim3(16, 32), 256, 0, stream>>>(
        Ao, Wprojb, out, 2048, 1024, 2048);
}

// Round 14
// 229.865 us; speedup vs baseline: 1.0514x; 1.0514x over previous
//
#include <hip/hip_runtime.h>

using bf16_t = __bf16;
typedef __bf16 bf16x4 __attribute__((ext_vector_type(4)));
typedef __bf16 bf16x8 __attribute__((ext_vector_type(8)));
typedef float floatx4 __attribute__((ext_vector_type(4)));

#define MFMA_BF16(a, b, c) __builtin_amdgcn_mfma_f32_16x16x32_bf16((a), (b), (c), 0, 0, 0)

__device__ __forceinline__ void async_ld16(bf16_t* lds_dst, const bf16_t* g_src) {
    __builtin_amdgcn_global_load_lds(
        (const __attribute__((address_space(1))) void*)g_src,
        (__attribute__((address_space(3))) void*)lds_dst, 16, 0, 0);
}

// ---------------------------------------------------------------------------
// Fused fp32->bf16 casts (x, Wqkv, Wproj) + lam, one launch.
// Blocks 0..1023: x; 1024..4095: Wqkv; 4096..5119: Wproj; 5120: lam.
// ---------------------------------------------------------------------------
__global__ __launch_bounds__(256) void cast_all(const float* __restrict__ x,
                                                const float* __restrict__ Wqkv,
                                                const float* __restrict__ Wproj,
                                                const float* __restrict__ lq1,
                                                const float* __restrict__ lq2,
                                                const float* __restrict__ lk1,
                                                const float* __restrict__ lk2,
                                                bf16_t* __restrict__ xb,
                                                bf16_t* __restrict__ Wqkvb,
                                                bf16_t* __restrict__ Wprojb,
                                                float* __restrict__ lamp) {
    const int b = blockIdx.x;
    if (b == 5120) {
        int l = threadIdx.x;
        if (l < 64) {
            float p1 = lq1[l] * lk1[l];
            float p2 = lq2[l] * lk2[l];
            #pragma unroll
            for (int d = 1; d < 64; d <<= 1) {
                p1 += __shfl_xor(p1, d);
                p2 += __shfl_xor(p2, d);
            }
            if (l == 0) *lamp = expf(p1) - expf(p2) + 0.2f;
        }
        return;
    }
    const float* src;
    bf16_t* dst;
    size_t i;
    if (b < 1024)      { src = x;     dst = xb;     i = (size_t)b * 256 + threadIdx.x; }
    else if (b < 4096) { src = Wqkv;  dst = Wqkvb;  i = (size_t)(b - 1024) * 256 + threadIdx.x; }
    else               { src = Wproj; dst = Wprojb; i = (size_t)(b - 4096) * 256 + threadIdx.x; }
    const floatx4 a = *(const floatx4*)(src + i * 8);
    const floatx4 c = *(const floatx4*)(src + i * 8 + 4);
    bf16x8 r;
    r[0] = (bf16_t)a[0]; r[1] = (bf16_t)a[1]; r[2] = (bf16_t)a[2]; r[3] = (bf16_t)a[3];
    r[4] = (bf16_t)c[0]; r[5] = (bf16_t)c[1]; r[6] = (bf16_t)c[2]; r[7] = (bf16_t)c[3];
    *(bf16x8*)(dst + i * 8) = r;
}

// ---------------------------------------------------------------------------
// QKV GEMM with FUSED ROTARY (v15, R12-proven — part of the 233.0 best).
// 128x128, BK=32, 4 waves, dbuf staging. Column remap: block bx covers
// head hh=bx&15 of component-pair p=bx>>4 (0=Q,1=K,2=V) with BOTH insts
// interleaved at j-granularity: staged B row (col c'=jt*16+rr) = p*2048 +
// (jt&1)*1024 + hh*64 + (jt>>1)*16 + rr. acc[i][2jp]/acc[i][2jp+1] hold
// the same (m,e) for inst0/inst1 -> rotation thread-local on f32 acc.
// FROZEN: BK=64@4w (-14us R7), 8w@BK32 (null R11), 8w+BK64 (-8us R13)
// all failed — the 2-phase 128^2 structure is at its regime ceiling.
// ---------------------------------------------------------------------------
__global__ __launch_bounds__(256) void gemm_qkv_rot(const bf16_t* __restrict__ A,
                                                    const bf16_t* __restrict__ B,
                                                    bf16_t* __restrict__ Qb,
                                                    bf16_t* __restrict__ Kb,
                                                    bf16_t* __restrict__ Vt) {
    constexpr int K = 1024, BM = 128, BK = 32;
    __shared__ __align__(16) bf16_t As[2][BM * BK];
    __shared__ __align__(16) bf16_t Bs[2][BM * BK];
    const int t = threadIdx.x;
    const int lane = t & 63, wave = t >> 6;
    const int q4 = lane >> 4, m16 = lane & 15;
    const int mblk = blockIdx.y * BM;
    const int p = blockIdx.x >> 4, hh = blockIdx.x & 15;
    const int pbase = p * 2048 + hh * 64;
    const int wr = wave >> 1, wc = wave & 1;

    auto stage = [&](int buf, int k0) {
        #pragma unroll
        for (int rr = 0; rr < 2; ++rr) {
            int f = rr * 256 + t;
            async_ld16(&As[buf][f * 8], &A[(size_t)(mblk + (f >> 2)) * K + k0 + (f & 3) * 8]);
        }
        #pragma unroll
        for (int rr = 0; rr < 2; ++rr) {
            int f = rr * 256 + t;
            int rp = f >> 2, jt = rp >> 4;
            int Brow = pbase + (jt & 1) * 1024 + ((jt >> 1) * 16) + (rp & 15);
            async_ld16(&Bs[buf][f * 8], &B[(size_t)Brow * K + k0 + (f & 3) * 8]);
        }
    };

    floatx4 acc[4][4] = {};
    stage(0, 0);

    for (int it = 0; it < 32; ++it) {
        const int cur = it & 1;
        __syncthreads();   // buf[cur] staged & visible; prev reads done
        if (it + 1 < 32) stage(cur ^ 1, (it + 1) * 32);

        bf16x8 a[4], b[4];
        #pragma unroll
        for (int i = 0; i < 4; ++i)
            a[i] = *(const bf16x8*)&As[cur][(wr * 64 + i * 16 + m16) * 32 + q4 * 8];
        #pragma unroll
        for (int j = 0; j < 4; ++j)
            b[j] = *(const bf16x8*)&Bs[cur][(wc * 64 + j * 16 + m16) * 32 + q4 * 8];
        __builtin_amdgcn_s_setprio(1);
        #pragma unroll
        for (int i = 0; i < 4; ++i)
            #pragma unroll
            for (int j = 0; j < 4; ++j)
                acc[i][j] = MFMA_BF16(a[i], b[j], acc[i][j]);
        __builtin_amdgcn_s_setprio(0);
    }

    if (p < 2) {
        bf16_t* dst = (p == 0) ? Qb : Kb;
        #pragma unroll
        for (int i = 0; i < 4; ++i) {
            int mbase = mblk + wr * 64 + i * 16 + q4 * 4;
            #pragma unroll
            for (int jp = 0; jp < 2; ++jp) {
                int e = (wc * 2 + jp) * 16 + m16;
                float invf = exp2f(-(float)e * (13.287712379549449f / 64.0f));
                #pragma unroll
                for (int r = 0; r < 4; ++r) {
                    int m = mbase + r;
                    float sn, cs;
                    sincosf((float)m * invf, &sn, &cs);
                    float v1 = acc[i][2 * jp][r], v2 = acc[i][2 * jp + 1][r];
                    dst[(size_t)(hh * 2048 + m) * 64 + e]        = (bf16_t)(v1 * cs - v2 * sn);
                    dst[(size_t)((16 + hh) * 2048 + m) * 64 + e] = (bf16_t)(v2 * cs + v1 * sn);
                }
            }
        }
    } else {
        #pragma unroll
        for (int i = 0; i < 4; ++i) {
            int mbase = mblk + wr * 64 + i * 16 + q4 * 4;
            #pragma unroll
            for (int j = 0; j < 4; ++j) {
                int inst = j & 1, e = (wc * 2 + (j >> 1)) * 16 + m16;
                bf16x4 pv;
                #pragma unroll
                for (int r = 0; r < 4; ++r) pv[r] = (bf16_t)acc[i][j][r];
                *(bf16x4*)&Vt[(size_t)(hh * 128 + inst * 64 + e) * 2048 + mbase] = pv;
            }
        }
    }
}

// ---------------------------------------------------------------------------
// GEMM (bf16), dbuf 2-phase — proj only. v17: BN 64->32 (grid 1024 = 4
// blocks/CU, was 2): doubles the cross-block pool hiding each block's
// stage+drain+barrier stall (R6's proven proj mechanism). LDS 24 KB.
// ---------------------------------------------------------------------------
template <int BM, int BN, int BK>
__global__ __launch_bounds__(256) void gemm_bt(const bf16_t* __restrict__ A,
                                               const bf16_t* __restrict__ B,
                                               float* __restrict__ C,
                                               int M, int N, int K) {
    constexpr int KC = BK / 32;
    constexpr int CH = BK / 8;
    constexpr int AR = BM * BK / 2048;
    constexpr int BR = BN * BK / 2048;
    __shared__ __align__(16) bf16_t As[2][BM * BK];
    __shared__ __align__(16) bf16_t Bs[2][BN * BK];
    const int t = threadIdx.x;
    const int lane = t & 63, wave = t >> 6;
    const int q4 = lane >> 4, m16 = lane & 15;
    const int mblk = blockIdx.y * BM, nblk = blockIdx.x * BN;
    const int wr = wave >> 1, wc = wave & 1;
    constexpr int WM = BM / 2, WN = BN / 2;
    constexpr int NI = WM / 16, NJ = WN / 16;

    auto stage = [&](int buf, int k0) {
        #pragma unroll
        for (int rr = 0; rr < AR; ++rr) {
            int f = rr * 256 + t;
            async_ld16(&As[buf][f * 8], &A[(size_t)(mblk + f / CH) * K + k0 + (f % CH) * 8]);
        }
        #pragma unroll
        for (int rr = 0; rr < BR; ++rr) {
            int f = rr * 256 + t;
            async_ld16(&Bs[buf][f * 8], &B[(size_t)(nblk + f / CH) * K + k0 + (f % CH) * 8]);
        }
    };

    floatx4 acc[NI][NJ] = {};
    stage(0, 0);  // prologue

    const int NTK = K / BK;
    for (int it = 0; it < NTK; ++it) {
        const int cur = it & 1;
        __syncthreads();
        if (it + 1 < NTK) stage(cur ^ 1, (it + 1) * BK);

        bf16x8 a[NI][KC], b[NJ][KC];
        #pragma unroll
        for (int i = 0; i < NI; ++i)
            #pragma unroll
            for (int kk = 0; kk < KC; ++kk)
                a[i][kk] = *(const bf16x8*)&As[cur][(wr * WM + i * 16 + m16) * BK + kk * 32 + q4 * 8];
        #pragma unroll
        for (int j = 0; j < NJ; ++j)
            #pragma unroll
            for (int kk = 0; kk < KC; ++kk)
                b[j][kk] = *(const bf16x8*)&Bs[cur][(wc * WN + j * 16 + m16) * BK + kk * 32 + q4 * 8];
        __builtin_amdgcn_s_setprio(1);
        #pragma unroll
        for (int i = 0; i < NI; ++i)
            #pragma unroll
            for (int j = 0; j < NJ; ++j)
                #pragma unroll
                for (int kk = 0; kk < KC; ++kk)
                    acc[i][j] = MFMA_BF16(a[i][kk], b[j][kk], acc[i][j]);
        __builtin_amdgcn_s_setprio(0);
    }

    #pragma unroll
    for (int i = 0; i < NI; ++i)
        #pragma unroll
        for (int j = 0; j < NJ; ++j) {
            int n = nblk + wc * WN + j * 16 + m16;
            int mbase = mblk + wr * WM + i * 16 + q4 * 4;
            #pragma unroll
            for (int r = 0; r < 4; ++r)
                C[(size_t)(mbase + r) * N + n] = acc[i][j][r];
        }
}

// ---------------------------------------------------------------------------
// Differential flash attention, v8 — FROZEN (proven 90.4-94us).
// Restructure history: v9 (cross-wave P + swapped QK) -> register blowup;
// v10 (K reg-prefetch) -> allocator sank loads across barrier; v12
// (cross-wave P + mid-iter barrier) -> lockstep killed wave-drift overlap.
// The wave-private P + single-barrier structure is load-bearing.
// ---------------------------------------------------------------------------
__global__ __launch_bounds__(512, 4) void flash_diff(const bf16_t* __restrict__ Qb,
                                                     const bf16_t* __restrict__ Kb,
                                                     const bf16_t* __restrict__ Vt,
                                                     const float* __restrict__ lamp,
                                                     bf16_t* __restrict__ Ao) {
    constexpr int N = 2048, BN = 64, NT = N / BN;  // 32 chunks
    __shared__ __align__(16) bf16_t smem[40960];   // 80 KB
    // buf b: Kf = smem + b*16384 (16 spans x 512), Vf = Kf + 8192
    bf16_t* Pf = smem + 32768;                     // [8 waves][2 half][512] 16 KB
    const int t = threadIdx.x, lane = t & 63, w = t >> 6;   // w in 0..7
    const int comp = w >> 2, w4 = w & 3;
    const int q4 = lane >> 4, m16 = lane & 15;
    const int Lb = blockIdx.x;
    const int virt = (Lb & 7) * 64 + (Lb >> 3);
    const int h = virt >> 5, qt = virt & 31;
    const float lam = *lamp;
    const float cexp = 0.125f * 1.4426950408889634f;  // scale * log2(e)

    // Q fragments for this wave's component (A-operand: m=m16 -> qrow)
    bf16x8 qf[2];
    const int qrow = qt * 64 + w4 * 16 + m16;
    #pragma unroll
    for (int kc = 0; kc < 2; ++kc)
        qf[kc] = *(const bf16x8*)&Qb[(size_t)((comp * 16 + h) * 2048 + qrow) * 64 + kc * 32 + q4 * 8];

    bf16x8 ones;
    #pragma unroll
    for (int j = 0; j < 8; ++j) ones[j] = (bf16_t)1.0f;

    floatx4 O[8] = {};
    floatx4 sm = {};

    auto stage = [&](bf16_t* Kd, bf16_t* Vd, int k0) {
        #pragma unroll
        for (int rr = 0; rr < 4; ++rr) {
            int idx = w * 4 + rr;
            if (idx < 16) {
                int i = idx >> 3, s = (idx >> 1) & 3, half = idx & 1;
                async_ld16(&Kd[idx * 512],
                           &Kb[(size_t)((i * 16 + h) * 2048 + k0 + 16 * s + m16) * 64 + half * 32 + q4 * 8]);
            } else {
                int v = idx - 16, tt = v >> 1, half = v & 1;
                async_ld16(&Vd[v * 512],
                           &Vt[(size_t)(h * 128 + tt * 16 + m16) * 2048 + k0 + half * 32 + q4 * 8]);
            }
        }
    };

    stage(smem, smem + 8192, 0);  // prologue: chunk 0 -> buf 0

    for (int it = 0; it < NT; ++it) {
        const int cur = it & 1;
        bf16_t* Kf = smem + cur * 16384;
        bf16_t* Vf = Kf + 8192;
        __syncthreads();
        if (it + 1 < NT) {
            bf16_t* Kn = smem + (cur ^ 1) * 16384;
            stage(Kn, Kn + 8192, (it + 1) * BN);
        }

        // ---- S = Q K^T (one component), p = exp2(S*cexp), swizzled P-store ----
        bf16_t* pw = &Pf[w * 1024];
        __builtin_amdgcn_s_setprio(1);
        #pragma unroll
        for (int s = 0; s < 4; ++s) {
            floatx4 sacc = {};
            const bf16x8 kf0 = *(const bf16x8*)&Kf[((comp * 4 + s) * 2 + 0) * 512 + lane * 8];
            const bf16x8 kf1 = *(const bf16x8*)&Kf[((comp * 4 + s) * 2 + 1) * 512 + lane * 8];
            sacc = MFMA_BF16(qf[0], kf0, sacc);  // D[qrow][key]
            sacc = MFMA_BF16(qf[1], kf1, sacc);
            __builtin_amdgcn_s_setprio(0);
            const int half = s >> 1, quad = (2 * s + (m16 >> 3)) & 3, jj = m16 & 7;
            #pragma unroll
            for (int r = 0; r < 4; ++r) {
                int u = quad * 16 + q4 * 4 + r;
                pw[half * 512 + (u ^ quad) * 8 + jj] = (bf16_t)exp2f(sacc[r] * cexp);
            }
            __builtin_amdgcn_s_setprio(1);
        }
        __builtin_amdgcn_s_setprio(0);
        // Pf region is wave-private: store->read ordered by intra-wave lgkmcnt.

        // ---- P reads (swizzled contiguous b128), row sums, PV ----
        bf16x8 pf[2];
        const int ur = lane ^ q4;  // (q4*16+m16) ^ (u>>4)
        pf[0] = *(const bf16x8*)&pw[0 * 512 + ur * 8];
        pf[1] = *(const bf16x8*)&pw[1 * 512 + ur * 8];
        sm = MFMA_BF16(pf[0], ones, sm);
        sm = MFMA_BF16(pf[1], ones, sm);
        __builtin_amdgcn_s_setprio(1);
        #pragma unroll
        for (int tt = 0; tt < 8; ++tt) {
            const bf16x8 vf0 = *(const bf16x8*)&Vf[(tt * 2 + 0) * 512 + lane * 8];
            const bf16x8 vf1 = *(const bf16x8*)&Vf[(tt * 2 + 1) * 512 + lane * 8];
            O[tt] = MFMA_BF16(pf[0], vf0, O[tt]);
            O[tt] = MFMA_BF16(pf[1], vf1, O[tt]);
        }
        __builtin_amdgcn_s_setprio(0);
    }

    // ---- epilogue: Ao[n][h*128+vc] = O0/l0 - lam*O1/l1 ----
    float inv[4];
    #pragma unroll
    for (int r = 0; r < 4; ++r) inv[r] = 1.0f / sm[r];

    float* Ff = (float*)smem;  // reuse buf0: [w4][col 128][row 16] f32 = 32 KB
    __syncthreads();           // all LDS traffic of last chunk done
    if (comp == 1) {
        #pragma unroll
        for (int tt = 0; tt < 8; ++tt) {
            floatx4 val;
            #pragma unroll
            for (int r = 0; r < 4; ++r) val[r] = lam * O[tt][r] * inv[r];
            *(floatx4*)&Ff[((w4 * 128 + tt * 16 + m16) << 4) + q4 * 4] = val;
        }
    }
    __syncthreads();
    if (comp == 0) {
        const int orow = qt * 64 + w4 * 16 + q4 * 4;
        #pragma unroll
        for (int tt = 0; tt < 8; ++tt) {
            const floatx4 v1 = *(const floatx4*)&Ff[((w4 * 128 + tt * 16 + m16) << 4) + q4 * 4];
            #pragma unroll
            for (int r = 0; r < 4; ++r) {
                float val = O[tt][r] * inv[r] - v1[r];
                Ao[(size_t)(orow + r) * 2048 + h * 128 + tt * 16 + m16] = (bf16_t)val;
            }
        }
    }
}

// ---------------------------------------------------------------------------
extern "C" void kernel_launch(void* const* d_in, const int* in_sizes, int n_in,
                              void* d_out, int out_size, void* d_ws, size_t ws_size,
                              hipStream_t stream) {
    const float* x     = (const float*)d_in[0];
    const float* Wqkv  = (const float*)d_in[1];
    const float* Wproj = (const float*)d_in[2];
    const float* lq1   = (const float*)d_in[3];
    const float* lq2   = (const float*)d_in[4];
    const float* lk1   = (const float*)d_in[5];
    const float* lk2   = (const float*)d_in[6];
    float* out = (float*)d_out;

    char* ws = (char*)d_ws;
    bf16_t* xb     = (bf16_t*)(ws);               //  4,194,304 B
    bf16_t* Ao     = (bf16_t*)(ws);               //  aliases xb/Wqkvb (dead post-QKV)
    bf16_t* Wqkvb  = (bf16_t*)(ws + 4194304);     // 12,582,912 B
    bf16_t* Wprojb = (bf16_t*)(ws + 16777216);    //  4,194,304 B
    bf16_t* Qb     = (bf16_t*)(ws + 20971520);    //  8,388,608 B
    bf16_t* Kb     = (bf16_t*)(ws + 29360128);    //  8,388,608 B
    bf16_t* Vt     = (bf16_t*)(ws + 37748736);    //  8,388,608 B
    float*  lamp   = (float*)(ws + 46137344);     //  4 B (total ~46.1 MB)

    // 4 launches: fused casts+lam, QKV GEMM w/ fused rotary (v15, R12),
    // flash (v8 frozen), proj (64x32 BK=64, dbuf, 4 blocks/CU).
    cast_all<<<5121, 256, 0, stream>>>(x, Wqkv, Wproj, lq1, lq2, lk1, lk2,
                                       xb, Wqkvb, Wprojb, lamp);
    gemm_qkv_rot<<<dim3(48, 16), 256, 0, stream>>>(xb, Wqkvb, Qb, Kb, Vt);
    flash_diff<<<512, 512, 0, stream>>>(Qb, Kb, Vt, lamp, Ao);
    gemm_bt<64, 32, 64><<<dim3(32, 32), 256, 0, stream>>>(
        Ao, Wprojb, out, 2048, 1024, 2048);
}